// Round 15
// baseline (104.167 us; speedup 1.0000x reference)
//
#include <hip/hip_runtime.h>

typedef __bf16 bf16;
typedef __bf16 bf16x8 __attribute__((ext_vector_type(8)));
typedef __bf16 bf16x4 __attribute__((ext_vector_type(4)));
typedef float f32x4 __attribute__((ext_vector_type(4)));

#define AS1(p) ((const __attribute__((address_space(1))) void*)(p))
#define AS3(p) ((__attribute__((address_space(3))) void*)(p))

__device__ __forceinline__ float sigm(float x) {
    return 1.f / (1.f + __expf(-x));
}
__device__ __forceinline__ float tanh_fast(float x) {
    float xx = fminf(fmaxf(x, -15.f), 15.f);
    float e = __expf(2.f * xx);
    return (e - 1.f) / (e + 1.f);
}
__device__ __forceinline__ bf16x8 pack8(float4 a, float4 b) {
    bf16x8 r;
    r[0] = (bf16)a.x; r[1] = (bf16)a.y; r[2] = (bf16)a.z; r[3] = (bf16)a.w;
    r[4] = (bf16)b.x; r[5] = (bf16)b.y; r[6] = (bf16)b.z; r[7] = (bf16)b.w;
    return r;
}

// ---------------------------------------------------------------------------
// Setup (verified R1/R5): bf16 weight copies.
//  Wcat [256][224] = [Wp | Wa | Wv] along K.
//  Wih_p/Whh_p [768][256]: gate-permuted rows. Permuted col c = chunk*48 +
//  gate*16 + jj maps to old row gate*256 + (chunk*16 + jj).
// ---------------------------------------------------------------------------
__global__ __launch_bounds__(256) void setup_weights(
    const float* __restrict__ Wp, const float* __restrict__ Wa, const float* __restrict__ Wv,
    const float* __restrict__ W_ih, const float* __restrict__ b_ih,
    const float* __restrict__ W_hh, const float* __restrict__ b_hh,
    bf16* __restrict__ Wcat, bf16* __restrict__ Wih_p, bf16* __restrict__ Whh_p,
    float* __restrict__ bih_p, float* __restrict__ bhh_p)
{
    int idx = blockIdx.x * 256 + threadIdx.x;
    if (idx < 256 * 224) {
        int out = idx / 224, k = idx % 224;
        float v = (k < 128) ? Wp[out * 128 + k]
                : (k < 192) ? Wa[out * 64 + (k - 128)]
                            : Wv[out * 32 + (k - 192)];
        Wcat[idx] = (bf16)v;
    }
    int i2 = idx - 256 * 224;
    if (i2 >= 0 && i2 < 768 * 256) {
        int c = i2 >> 8, k = i2 & 255;
        int chunk = c / 48, gate = (c % 48) / 16, jj = c % 16;
        int oldrow = gate * 256 + chunk * 16 + jj;
        Wih_p[i2] = (bf16)W_ih[oldrow * 256 + k];
        Whh_p[i2] = (bf16)W_hh[oldrow * 256 + k];
        if (k == 0) { bih_p[c] = b_ih[oldrow]; bhh_p[c] = b_hh[oldrow]; }
    }
}

// ---------------------------------------------------------------------------
// K1 (verified R1/R5): emb[slot][256] = x_cat(slot) @ Wcat^T + bias(type).
// ---------------------------------------------------------------------------
__global__ __launch_bounds__(256) void emb_kernel(
    const float* __restrict__ px, const float* __restrict__ ax_, const float* __restrict__ vx,
    const float* __restrict__ bp, const float* __restrict__ ba, const float* __restrict__ bv,
    const int* __restrict__ type_ids, const int* __restrict__ node_ids,
    const bf16* __restrict__ Wcat, bf16* __restrict__ emb)
{
    __shared__ bf16 At[32 * 232];
    __shared__ float biasl[768];
    const int tid = threadIdx.x;

    biasl[tid] = bp[tid];
    biasl[256 + tid] = ba[tid];
    biasl[512 + tid] = bv[tid];

    unsigned int* Az = (unsigned int*)At;
    #pragma unroll
    for (int i = 0; i < 15; i++) { int z = i * 256 + tid; if (z < 3712) Az[z] = 0u; }
    __syncthreads();

    const int slot0 = blockIdx.x * 32;
    {
        const int s = tid >> 3, g = tid & 7;
        const int slot = slot0 + s;
        const int t = type_ids[slot];
        const long n = (long)node_ids[slot];
        bf16* Arow = At + s * 232;
        if (t == 0) {
            const float4* src = (const float4*)(px + n * 128);
            float4 v0 = src[g * 4 + 0], v1 = src[g * 4 + 1], v2 = src[g * 4 + 2], v3 = src[g * 4 + 3];
            *(bf16x8*)(Arow + 16 * g) = pack8(v0, v1);
            *(bf16x8*)(Arow + 16 * g + 8) = pack8(v2, v3);
        } else if (t == 1) {
            const float4* src = (const float4*)(ax_ + n * 64);
            float4 v0 = src[g * 2 + 0], v1 = src[g * 2 + 1];
            *(bf16x8*)(Arow + 128 + 8 * g) = pack8(v0, v1);
        } else {
            float4 v0 = ((const float4*)(vx + n * 32))[g];
            bf16x4 r4; r4[0] = (bf16)v0.x; r4[1] = (bf16)v0.y; r4[2] = (bf16)v0.z; r4[3] = (bf16)v0.w;
            *(bf16x4*)(Arow + 192 + 4 * g) = r4;
        }
    }
    __syncthreads();

    const int w = tid >> 6, lane = tid & 63, l15 = lane & 15, l4 = lane >> 4;
    f32x4 zv = {0.f, 0.f, 0.f, 0.f};
    f32x4 acc[2][4];
    #pragma unroll
    for (int i = 0; i < 2; i++)
        #pragma unroll
        for (int j = 0; j < 4; j++) acc[i][j] = zv;

    #pragma unroll
    for (int k0 = 0; k0 < 224; k0 += 32) {
        bf16x8 a[2], b[4];
        #pragma unroll
        for (int am = 0; am < 2; am++) {
            int r = 16 * am + l15;
            a[am] = *(const bf16x8*)(At + r * 232 + k0 + 8 * l4);
        }
        #pragma unroll
        for (int bn = 0; bn < 4; bn++) {
            int o = 64 * w + 16 * bn + l15;
            b[bn] = *(const bf16x8*)(Wcat + o * 224 + k0 + 8 * l4);
        }
        #pragma unroll
        for (int am = 0; am < 2; am++)
            #pragma unroll
            for (int bn = 0; bn < 4; bn++)
                acc[am][bn] = __builtin_amdgcn_mfma_f32_16x16x32_bf16(a[am], b[bn], acc[am][bn], 0, 0, 0);
    }

    #pragma unroll
    for (int am = 0; am < 2; am++)
        #pragma unroll
        for (int bn = 0; bn < 4; bn++) {
            int o = 64 * w + 16 * bn + l15;
            #pragma unroll
            for (int r = 0; r < 4; r++) {
                int slot = slot0 + 16 * am + 4 * l4 + r;
                int t = type_ids[slot];
                emb[((size_t)slot << 8) + o] = (bf16)(acc[am][bn][r] + biasl[t * 256 + o]);
            }
        }
}

// ---------------------------------------------------------------------------
// K2 (R15): verified R12 tile (128x96) + step-0 fold + LENGTH-MASKED writes:
// gx row (path*8+step) is stored only if step < lengths[path] — dead rows
// (44% avg) keep ws poison and are never read (gru guards its loads).
// ---------------------------------------------------------------------------
__global__ __launch_bounds__(256) void gx_kernel(
    const bf16* __restrict__ Am, const bf16* __restrict__ Wih_p,
    const float* __restrict__ bih_p, const float* __restrict__ bhh_p,
    const int* __restrict__ lengths, bf16* __restrict__ gx,
    bf16* __restrict__ h1b)
{
    __shared__ bf16 At[128 * 64];
    __shared__ bf16 Bt[96 * 64];
    const int tid = threadIdx.x;
    const int row0 = blockIdx.x * 128;
    const int c0 = blockIdx.y * 96;
    const int w = tid >> 6, lane = tid & 63, l15 = lane & 15, l4 = lane >> 4;
    const int wm = w >> 1, wn = w & 1;

    f32x4 zv = {0.f, 0.f, 0.f, 0.f};
    f32x4 acc[4][3];
    #pragma unroll
    for (int i = 0; i < 4; i++)
        #pragma unroll
        for (int j = 0; j < 3; j++) acc[i][j] = zv;

    for (int k0 = 0; k0 < 256; k0 += 64) {
        #pragma unroll
        for (int i = 0; i < 4; i++) {
            int g = i * 256 + tid; int r = g >> 3, s = g & 7;
            const bf16* src = Am + ((size_t)(row0 + r) << 8) + k0 + ((s ^ (r & 7)) << 3);
            __builtin_amdgcn_global_load_lds(AS1(src), AS3(At + g * 8), 16, 0, 0);
        }
        #pragma unroll
        for (int i = 0; i < 3; i++) {
            int g = i * 256 + tid; int r = g >> 3, s = g & 7;
            const bf16* src = Wih_p + ((size_t)(c0 + r) << 8) + k0 + ((s ^ (r & 7)) << 3);
            __builtin_amdgcn_global_load_lds(AS1(src), AS3(Bt + g * 8), 16, 0, 0);
        }
        __syncthreads();
        #pragma unroll
        for (int kk = 0; kk < 64; kk += 32) {
            int sbase = kk >> 3;
            bf16x8 a[4], b[3];
            #pragma unroll
            for (int am = 0; am < 4; am++) {
                int r = 64 * wm + 16 * am + l15;
                a[am] = *(const bf16x8*)(At + r * 64 + (((sbase + l4) ^ (r & 7)) << 3));
            }
            #pragma unroll
            for (int bn = 0; bn < 3; bn++) {
                int c = 48 * wn + 16 * bn + l15;
                b[bn] = *(const bf16x8*)(Bt + c * 64 + (((sbase + l4) ^ (c & 7)) << 3));
            }
            #pragma unroll
            for (int am = 0; am < 4; am++)
                #pragma unroll
                for (int bn = 0; bn < 3; bn++)
                    acc[am][bn] = __builtin_amdgcn_mfma_f32_16x16x32_bf16(a[am], b[bn], acc[am][bn], 0, 0, 0);
        }
        __syncthreads();
    }

    const int cbase = c0 + 48 * wn + l15;
    float bi[3];
    #pragma unroll
    for (int bn = 0; bn < 3; bn++) bi[bn] = bih_p[cbase + 16 * bn];

    // length-masked gx writes: this thread's 4 rows per am share one path
    // (rows rowb..rowb+3, steps 4*(l4&1)+r)
    const int sb = 4 * (l4 & 1);
    #pragma unroll
    for (int am = 0; am < 4; am++) {
        int rowb = row0 + 64 * wm + 16 * am + 4 * l4;
        int lenp = lengths[rowb >> 3];
        #pragma unroll
        for (int bn = 0; bn < 3; bn++) {
            int c = cbase + 16 * bn;
            #pragma unroll
            for (int r = 0; r < 4; r++) {
                if (sb + r < lenp)
                    gx[(size_t)(rowb + r) * 768 + c] = (bf16)(acc[am][bn][r] + bi[bn]);
            }
        }
    }

    // step-0 GRU fold (verified R12): rows row%8==0 -> r=0, l4 even
    if ((l4 & 1) == 0) {
        const float bh0 = bhh_p[cbase], bh1 = bhh_p[cbase + 16], bh2 = bhh_p[cbase + 32];
        const int j = ((blockIdx.y * 2 + wn) << 4) + l15;
        #pragma unroll
        for (int am = 0; am < 4; am++) {
            int row = row0 + 64 * wm + 16 * am + 4 * l4;
            int path = row >> 3;
            float xr = acc[am][0][0] + bi[0];
            float xz = acc[am][1][0] + bi[1];
            float xn = acc[am][2][0] + bi[2];
            float rr = sigm(xr + bh0);
            float zz = sigm(xz + bh1);
            float nn = tanh_fast(xn + rr * bh2);
            float hnew = (0 < lengths[path]) ? (1.f - zz) * nn : 0.f;
            h1b[((size_t)path << 8) + j] = (bf16)hnew;
        }
    }
}

// ---------------------------------------------------------------------------
// K3 (R15): one GRU step (1..7).  R12-verified body (single-buffered, 32x96,
// grid 128x8, 4 blocks/CU, 16KB LDS, hoisted operands, bf16 h) + length-
// guarded gate loads (rows with step >= len are frozen; their gx rows are
// unwritten poison and must not be read).
// ---------------------------------------------------------------------------
__global__ __launch_bounds__(256, 4) void gru_kernel(
    const bf16* __restrict__ hin_b,
    const bf16* __restrict__ Whh_p, const float* __restrict__ bhh_p,
    const bf16* __restrict__ gx, const int* __restrict__ lengths,
    bf16* __restrict__ hout_b, int step)
{
    __shared__ bf16 At[32 * 64];
    __shared__ bf16 Bt[96 * 64];
    const int tid = threadIdx.x;
    const int row0 = blockIdx.x * 32;
    const int c0 = blockIdx.y * 96;
    const int w = tid >> 6, lane = tid & 63, l15 = lane & 15, l4 = lane >> 4;
    const int wm = w >> 1, wn = w & 1;

    // ---- hoisted epilogue operands (complete under the K-loop) ----
    const int cbase = c0 + 48 * wn + l15;
    const int j = ((blockIdx.y * 2 + wn) << 4) + l15;
    float xr_[4], xz_[4], xn_[4], hold_[4];
    int len_[4];
    #pragma unroll
    for (int r = 0; r < 4; r++) {
        int row = row0 + 16 * wm + 4 * l4 + r;
        len_[r] = lengths[row];
        hold_[r] = (float)hin_b[((size_t)row << 8) + j];
        if (step < len_[r]) {
            const bf16* gxp = gx + ((size_t)(row * 8 + step)) * 768 + cbase;
            xr_[r] = (float)gxp[0]; xz_[r] = (float)gxp[16]; xn_[r] = (float)gxp[32];
        } else {
            xr_[r] = 0.f; xz_[r] = 0.f; xn_[r] = 0.f;
        }
    }
    const float bh0 = bhh_p[cbase], bh1 = bhh_p[cbase + 16], bh2 = bhh_p[cbase + 32];

    f32x4 zv = {0.f, 0.f, 0.f, 0.f};
    f32x4 acc[3];
    #pragma unroll
    for (int i = 0; i < 3; i++) acc[i] = zv;

    for (int k0 = 0; k0 < 256; k0 += 64) {
        {
            int g = tid; int r = g >> 3, s = g & 7;
            const bf16* src = hin_b + ((size_t)(row0 + r) << 8) + k0 + ((s ^ (r & 7)) << 3);
            __builtin_amdgcn_global_load_lds(AS1(src), AS3(At + g * 8), 16, 0, 0);
        }
        #pragma unroll
        for (int i = 0; i < 3; i++) {
            int g = i * 256 + tid; int r = g >> 3, s = g & 7;
            const bf16* src = Whh_p + ((size_t)(c0 + r) << 8) + k0 + ((s ^ (r & 7)) << 3);
            __builtin_amdgcn_global_load_lds(AS1(src), AS3(Bt + g * 8), 16, 0, 0);
        }
        __syncthreads();
        #pragma unroll
        for (int kk = 0; kk < 64; kk += 32) {
            int sbase = kk >> 3;
            bf16x8 a, b[3];
            {
                int r = 16 * wm + l15;
                a = *(const bf16x8*)(At + r * 64 + (((sbase + l4) ^ (r & 7)) << 3));
            }
            #pragma unroll
            for (int bn = 0; bn < 3; bn++) {
                int c = 48 * wn + 16 * bn + l15;
                b[bn] = *(const bf16x8*)(Bt + c * 64 + (((sbase + l4) ^ (c & 7)) << 3));
            }
            #pragma unroll
            for (int bn = 0; bn < 3; bn++)
                acc[bn] = __builtin_amdgcn_mfma_f32_16x16x32_bf16(a, b[bn], acc[bn], 0, 0, 0);
        }
        __syncthreads();
    }

    #pragma unroll
    for (int r = 0; r < 4; r++) {
        int row = row0 + 16 * wm + 4 * l4 + r;
        float rr = sigm(xr_[r] + acc[0][r] + bh0);
        float zz = sigm(xz_[r] + acc[1][r] + bh1);
        float nn = tanh_fast(xn_[r] + rr * (acc[2][r] + bh2));
        float hnew = (step < len_[r]) ? ((1.f - zz) * nn + zz * hold_[r]) : hold_[r];
        hout_b[((size_t)row << 8) + j] = (bf16)hnew;
    }
}

// ---------------------------------------------------------------------------
// K4 (verified R8): logits = h_final(bf16) @ Wc^T + bc
// ---------------------------------------------------------------------------
__global__ __launch_bounds__(256) void cls_kernel(
    const bf16* __restrict__ h, const float* __restrict__ Wc,
    const float* __restrict__ bc, float* __restrict__ out)
{
    __shared__ float Wl[8 * 260];
    int tid = threadIdx.x;
    for (int i = tid; i < 2048; i += 256) { int c = i >> 8, k = i & 255; Wl[c * 260 + k] = Wc[i]; }
    __syncthreads();
    int o = blockIdx.x * 256 + tid;
    int row = o >> 3, c = o & 7;
    const bf16x8* hr = (const bf16x8*)(h + ((size_t)row << 8));
    const float* wr = Wl + c * 260;
    float acc1 = 0.f;
    #pragma unroll 8
    for (int k = 0; k < 32; k++) {
        bf16x8 a = hr[k];
        const float* b = wr + 8 * k;
        acc1 += (float)a[0] * b[0] + (float)a[1] * b[1] + (float)a[2] * b[2] + (float)a[3] * b[3]
              + (float)a[4] * b[4] + (float)a[5] * b[5] + (float)a[6] * b[6] + (float)a[7] * b[7];
    }
    out[o] = acc1 + bc[c];
}

extern "C" void kernel_launch(void* const* d_in, const int* in_sizes, int n_in,
                              void* d_out, int out_size, void* d_ws, size_t ws_size,
                              hipStream_t stream) {
    if (n_in < 18) return;
    const float* paper_x  = (const float*)d_in[0];
    const float* author_x = (const float*)d_in[1];
    const float* venue_x  = (const float*)d_in[2];
    const float* Wp   = (const float*)d_in[3];
    const float* bp   = (const float*)d_in[4];
    const float* Wa   = (const float*)d_in[5];
    const float* ba   = (const float*)d_in[6];
    const float* Wv   = (const float*)d_in[7];
    const float* bv   = (const float*)d_in[8];
    const float* W_ih = (const float*)d_in[9];
    const float* b_ih = (const float*)d_in[10];
    const float* W_hh = (const float*)d_in[11];
    const float* b_hh = (const float*)d_in[12];
    const float* Wc   = (const float*)d_in[13];
    const float* bc   = (const float*)d_in[14];
    const int* type_ids = (const int*)d_in[15];
    const int* node_ids = (const int*)d_in[16];
    const int* lengths  = (const int*)d_in[17];

    char* ws = (char*)d_ws;
    size_t off = 0;
    bf16* Wcat  = (bf16*)(ws + off); off += (size_t)256 * 224 * 2;
    bf16* Wih_p = (bf16*)(ws + off); off += (size_t)768 * 256 * 2;
    bf16* Whh_p = (bf16*)(ws + off); off += (size_t)768 * 256 * 2;
    float* bih_p = (float*)(ws + off); off += 768 * 4;
    float* bhh_p = (float*)(ws + off); off += 768 * 4;
    off = (off + 255) & ~(size_t)255;
    bf16* emb = (bf16*)(ws + off); off += (size_t)32768 * 256 * 2;
    bf16* gx  = (bf16*)(ws + off); off += (size_t)32768 * 768 * 2;
    bf16* h0b = (bf16*)(ws + off); off += (size_t)4096 * 256 * 2;
    bf16* h1b = (bf16*)(ws + off); off += (size_t)4096 * 256 * 2;
    if (ws_size < off) return;

    setup_weights<<<992, 256, 0, stream>>>(Wp, Wa, Wv, W_ih, b_ih, W_hh, b_hh,
                                           Wcat, Wih_p, Whh_p, bih_p, bhh_p);
    emb_kernel<<<1024, 256, 0, stream>>>(paper_x, author_x, venue_x, bp, ba, bv,
                                         type_ids, node_ids, Wcat, emb);
    // gx + fused step 0 (writes h1b); dead rows (step>=len) left unwritten
    gx_kernel<<<dim3(256, 8), 256, 0, stream>>>(emb, Wih_p, bih_p, bhh_p,
                                                lengths, gx, h1b);

    // steps 1..7 ping-pong; final lands in h0b
    for (int l = 1; l < 8; l++) {
        const bf16* hib = (l & 1) ? h1b : h0b;
        bf16* hob = (l & 1) ? h0b : h1b;
        gru_kernel<<<dim3(128, 8), 256, 0, stream>>>(hib, Whh_p, bhh_p, gx,
                                                     lengths, hob, l);
    }
    cls_kernel<<<128, 256, 0, stream>>>(h0b, Wc, bc, (float*)d_out);
}

// Round 16
// 99.994 us; speedup vs baseline: 1.0417x; 1.0417x over previous
//
#include <hip/hip_runtime.h>

typedef __bf16 bf16;
typedef __bf16 bf16x8 __attribute__((ext_vector_type(8)));
typedef __bf16 bf16x4 __attribute__((ext_vector_type(4)));
typedef float f32x4 __attribute__((ext_vector_type(4)));

#define AS1(p) ((const __attribute__((address_space(1))) void*)(p))
#define AS3(p) ((__attribute__((address_space(3))) void*)(p))

__device__ __forceinline__ float sigm(float x) {
    return 1.f / (1.f + __expf(-x));
}
__device__ __forceinline__ float tanh_fast(float x) {
    float xx = fminf(fmaxf(x, -15.f), 15.f);
    float e = __expf(2.f * xx);
    return (e - 1.f) / (e + 1.f);
}
__device__ __forceinline__ bf16x8 pack8(float4 a, float4 b) {
    bf16x8 r;
    r[0] = (bf16)a.x; r[1] = (bf16)a.y; r[2] = (bf16)a.z; r[3] = (bf16)a.w;
    r[4] = (bf16)b.x; r[5] = (bf16)b.y; r[6] = (bf16)b.z; r[7] = (bf16)b.w;
    return r;
}

// ---------------------------------------------------------------------------
// Setup (verified R1/R5): bf16 weight copies.
//  Wcat [256][224] = [Wp | Wa | Wv] along K.
//  Wih_p/Whh_p [768][256]: gate-permuted rows. Permuted col c = chunk*48 +
//  gate*16 + jj maps to old row gate*256 + (chunk*16 + jj).
// ---------------------------------------------------------------------------
__global__ __launch_bounds__(256) void setup_weights(
    const float* __restrict__ Wp, const float* __restrict__ Wa, const float* __restrict__ Wv,
    const float* __restrict__ W_ih, const float* __restrict__ b_ih,
    const float* __restrict__ W_hh, const float* __restrict__ b_hh,
    bf16* __restrict__ Wcat, bf16* __restrict__ Wih_p, bf16* __restrict__ Whh_p,
    float* __restrict__ bih_p, float* __restrict__ bhh_p)
{
    int idx = blockIdx.x * 256 + threadIdx.x;
    if (idx < 256 * 224) {
        int out = idx / 224, k = idx % 224;
        float v = (k < 128) ? Wp[out * 128 + k]
                : (k < 192) ? Wa[out * 64 + (k - 128)]
                            : Wv[out * 32 + (k - 192)];
        Wcat[idx] = (bf16)v;
    }
    int i2 = idx - 256 * 224;
    if (i2 >= 0 && i2 < 768 * 256) {
        int c = i2 >> 8, k = i2 & 255;
        int chunk = c / 48, gate = (c % 48) / 16, jj = c % 16;
        int oldrow = gate * 256 + chunk * 16 + jj;
        Wih_p[i2] = (bf16)W_ih[oldrow * 256 + k];
        Whh_p[i2] = (bf16)W_hh[oldrow * 256 + k];
        if (k == 0) { bih_p[c] = b_ih[oldrow]; bhh_p[c] = b_hh[oldrow]; }
    }
}

// ---------------------------------------------------------------------------
// K1 (verified R1/R5): emb[slot][256] = x_cat(slot) @ Wcat^T + bias(type).
// ---------------------------------------------------------------------------
__global__ __launch_bounds__(256) void emb_kernel(
    const float* __restrict__ px, const float* __restrict__ ax_, const float* __restrict__ vx,
    const float* __restrict__ bp, const float* __restrict__ ba, const float* __restrict__ bv,
    const int* __restrict__ type_ids, const int* __restrict__ node_ids,
    const bf16* __restrict__ Wcat, bf16* __restrict__ emb)
{
    __shared__ bf16 At[32 * 232];
    __shared__ float biasl[768];
    const int tid = threadIdx.x;

    biasl[tid] = bp[tid];
    biasl[256 + tid] = ba[tid];
    biasl[512 + tid] = bv[tid];

    unsigned int* Az = (unsigned int*)At;
    #pragma unroll
    for (int i = 0; i < 15; i++) { int z = i * 256 + tid; if (z < 3712) Az[z] = 0u; }
    __syncthreads();

    const int slot0 = blockIdx.x * 32;
    {
        const int s = tid >> 3, g = tid & 7;
        const int slot = slot0 + s;
        const int t = type_ids[slot];
        const long n = (long)node_ids[slot];
        bf16* Arow = At + s * 232;
        if (t == 0) {
            const float4* src = (const float4*)(px + n * 128);
            float4 v0 = src[g * 4 + 0], v1 = src[g * 4 + 1], v2 = src[g * 4 + 2], v3 = src[g * 4 + 3];
            *(bf16x8*)(Arow + 16 * g) = pack8(v0, v1);
            *(bf16x8*)(Arow + 16 * g + 8) = pack8(v2, v3);
        } else if (t == 1) {
            const float4* src = (const float4*)(ax_ + n * 64);
            float4 v0 = src[g * 2 + 0], v1 = src[g * 2 + 1];
            *(bf16x8*)(Arow + 128 + 8 * g) = pack8(v0, v1);
        } else {
            float4 v0 = ((const float4*)(vx + n * 32))[g];
            bf16x4 r4; r4[0] = (bf16)v0.x; r4[1] = (bf16)v0.y; r4[2] = (bf16)v0.z; r4[3] = (bf16)v0.w;
            *(bf16x4*)(Arow + 192 + 4 * g) = r4;
        }
    }
    __syncthreads();

    const int w = tid >> 6, lane = tid & 63, l15 = lane & 15, l4 = lane >> 4;
    f32x4 zv = {0.f, 0.f, 0.f, 0.f};
    f32x4 acc[2][4];
    #pragma unroll
    for (int i = 0; i < 2; i++)
        #pragma unroll
        for (int j = 0; j < 4; j++) acc[i][j] = zv;

    #pragma unroll
    for (int k0 = 0; k0 < 224; k0 += 32) {
        bf16x8 a[2], b[4];
        #pragma unroll
        for (int am = 0; am < 2; am++) {
            int r = 16 * am + l15;
            a[am] = *(const bf16x8*)(At + r * 232 + k0 + 8 * l4);
        }
        #pragma unroll
        for (int bn = 0; bn < 4; bn++) {
            int o = 64 * w + 16 * bn + l15;
            b[bn] = *(const bf16x8*)(Wcat + o * 224 + k0 + 8 * l4);
        }
        #pragma unroll
        for (int am = 0; am < 2; am++)
            #pragma unroll
            for (int bn = 0; bn < 4; bn++)
                acc[am][bn] = __builtin_amdgcn_mfma_f32_16x16x32_bf16(a[am], b[bn], acc[am][bn], 0, 0, 0);
    }

    #pragma unroll
    for (int am = 0; am < 2; am++)
        #pragma unroll
        for (int bn = 0; bn < 4; bn++) {
            int o = 64 * w + 16 * bn + l15;
            #pragma unroll
            for (int r = 0; r < 4; r++) {
                int slot = slot0 + 16 * am + 4 * l4 + r;
                int t = type_ids[slot];
                emb[((size_t)slot << 8) + o] = (bf16)(acc[am][bn][r] + biasl[t * 256 + o]);
            }
        }
}

// ---------------------------------------------------------------------------
// K2 (verified R12): gx = emb @ Wih_p^T + bih_p, 128x96 tile + step-0 fold.
// ---------------------------------------------------------------------------
__global__ __launch_bounds__(256) void gx_kernel(
    const bf16* __restrict__ Am, const bf16* __restrict__ Wih_p,
    const float* __restrict__ bih_p, const float* __restrict__ bhh_p,
    const int* __restrict__ lengths, bf16* __restrict__ gx,
    bf16* __restrict__ h1b)
{
    __shared__ bf16 At[128 * 64];
    __shared__ bf16 Bt[96 * 64];
    const int tid = threadIdx.x;
    const int row0 = blockIdx.x * 128;
    const int c0 = blockIdx.y * 96;
    const int w = tid >> 6, lane = tid & 63, l15 = lane & 15, l4 = lane >> 4;
    const int wm = w >> 1, wn = w & 1;

    f32x4 zv = {0.f, 0.f, 0.f, 0.f};
    f32x4 acc[4][3];
    #pragma unroll
    for (int i = 0; i < 4; i++)
        #pragma unroll
        for (int j = 0; j < 3; j++) acc[i][j] = zv;

    for (int k0 = 0; k0 < 256; k0 += 64) {
        #pragma unroll
        for (int i = 0; i < 4; i++) {
            int g = i * 256 + tid; int r = g >> 3, s = g & 7;
            const bf16* src = Am + ((size_t)(row0 + r) << 8) + k0 + ((s ^ (r & 7)) << 3);
            __builtin_amdgcn_global_load_lds(AS1(src), AS3(At + g * 8), 16, 0, 0);
        }
        #pragma unroll
        for (int i = 0; i < 3; i++) {
            int g = i * 256 + tid; int r = g >> 3, s = g & 7;
            const bf16* src = Wih_p + ((size_t)(c0 + r) << 8) + k0 + ((s ^ (r & 7)) << 3);
            __builtin_amdgcn_global_load_lds(AS1(src), AS3(Bt + g * 8), 16, 0, 0);
        }
        __syncthreads();
        #pragma unroll
        for (int kk = 0; kk < 64; kk += 32) {
            int sbase = kk >> 3;
            bf16x8 a[4], b[3];
            #pragma unroll
            for (int am = 0; am < 4; am++) {
                int r = 64 * wm + 16 * am + l15;
                a[am] = *(const bf16x8*)(At + r * 64 + (((sbase + l4) ^ (r & 7)) << 3));
            }
            #pragma unroll
            for (int bn = 0; bn < 3; bn++) {
                int c = 48 * wn + 16 * bn + l15;
                b[bn] = *(const bf16x8*)(Bt + c * 64 + (((sbase + l4) ^ (c & 7)) << 3));
            }
            #pragma unroll
            for (int am = 0; am < 4; am++)
                #pragma unroll
                for (int bn = 0; bn < 3; bn++)
                    acc[am][bn] = __builtin_amdgcn_mfma_f32_16x16x32_bf16(a[am], b[bn], acc[am][bn], 0, 0, 0);
        }
        __syncthreads();
    }

    const int cbase = c0 + 48 * wn + l15;
    float bi[3];
    #pragma unroll
    for (int bn = 0; bn < 3; bn++) bi[bn] = bih_p[cbase + 16 * bn];

    #pragma unroll
    for (int am = 0; am < 4; am++)
        #pragma unroll
        for (int bn = 0; bn < 3; bn++) {
            int c = cbase + 16 * bn;
            #pragma unroll
            for (int r = 0; r < 4; r++) {
                int row = row0 + 64 * wm + 16 * am + 4 * l4 + r;
                gx[(size_t)row * 768 + c] = (bf16)(acc[am][bn][r] + bi[bn]);
            }
        }

    // step-0 GRU fold (verified R12): rows row%8==0 -> r=0, l4 even
    if ((l4 & 1) == 0) {
        const float bh0 = bhh_p[cbase], bh1 = bhh_p[cbase + 16], bh2 = bhh_p[cbase + 32];
        const int j = ((blockIdx.y * 2 + wn) << 4) + l15;
        #pragma unroll
        for (int am = 0; am < 4; am++) {
            int row = row0 + 64 * wm + 16 * am + 4 * l4;
            int path = row >> 3;
            float xr = acc[am][0][0] + bi[0];
            float xz = acc[am][1][0] + bi[1];
            float xn = acc[am][2][0] + bi[2];
            float rr = sigm(xr + bh0);
            float zz = sigm(xz + bh1);
            float nn = tanh_fast(xn + rr * bh2);
            float hnew = (0 < lengths[path]) ? (1.f - zz) * nn : 0.f;
            h1b[((size_t)path << 8) + j] = (bf16)hnew;
        }
    }
}

// ---------------------------------------------------------------------------
// K3 (verified R8/R12): one GRU step (1..7).  32 rows x 96 perm-cols per
// block, grid 128x8 = 1024 blocks = 4 blocks/CU, LDS 16KB, hoisted epilogue
// operands, bf16-only h carry.
// ---------------------------------------------------------------------------
__global__ __launch_bounds__(256, 4) void gru_kernel(
    const bf16* __restrict__ hin_b,
    const bf16* __restrict__ Whh_p, const float* __restrict__ bhh_p,
    const bf16* __restrict__ gx, const int* __restrict__ lengths,
    bf16* __restrict__ hout_b, int step)
{
    __shared__ bf16 At[32 * 64];
    __shared__ bf16 Bt[96 * 64];
    const int tid = threadIdx.x;
    const int row0 = blockIdx.x * 32;
    const int c0 = blockIdx.y * 96;
    const int w = tid >> 6, lane = tid & 63, l15 = lane & 15, l4 = lane >> 4;
    const int wm = w >> 1, wn = w & 1;

    // ---- hoisted epilogue operands (complete under the K-loop) ----
    const int cbase = c0 + 48 * wn + l15;
    const int j = ((blockIdx.y * 2 + wn) << 4) + l15;
    float xr_[4], xz_[4], xn_[4], hold_[4];
    int len_[4];
    #pragma unroll
    for (int r = 0; r < 4; r++) {
        int row = row0 + 16 * wm + 4 * l4 + r;
        const bf16* gxp = gx + ((size_t)(row * 8 + step)) * 768 + cbase;
        xr_[r] = (float)gxp[0]; xz_[r] = (float)gxp[16]; xn_[r] = (float)gxp[32];
        hold_[r] = (float)hin_b[((size_t)row << 8) + j];
        len_[r] = lengths[row];
    }
    const float bh0 = bhh_p[cbase], bh1 = bhh_p[cbase + 16], bh2 = bhh_p[cbase + 32];

    f32x4 zv = {0.f, 0.f, 0.f, 0.f};
    f32x4 acc[3];
    #pragma unroll
    for (int i = 0; i < 3; i++) acc[i] = zv;

    for (int k0 = 0; k0 < 256; k0 += 64) {
        {
            int g = tid; int r = g >> 3, s = g & 7;
            const bf16* src = hin_b + ((size_t)(row0 + r) << 8) + k0 + ((s ^ (r & 7)) << 3);
            __builtin_amdgcn_global_load_lds(AS1(src), AS3(At + g * 8), 16, 0, 0);
        }
        #pragma unroll
        for (int i = 0; i < 3; i++) {
            int g = i * 256 + tid; int r = g >> 3, s = g & 7;
            const bf16* src = Whh_p + ((size_t)(c0 + r) << 8) + k0 + ((s ^ (r & 7)) << 3);
            __builtin_amdgcn_global_load_lds(AS1(src), AS3(Bt + g * 8), 16, 0, 0);
        }
        __syncthreads();
        #pragma unroll
        for (int kk = 0; kk < 64; kk += 32) {
            int sbase = kk >> 3;
            bf16x8 a, b[3];
            {
                int r = 16 * wm + l15;
                a = *(const bf16x8*)(At + r * 64 + (((sbase + l4) ^ (r & 7)) << 3));
            }
            #pragma unroll
            for (int bn = 0; bn < 3; bn++) {
                int c = 48 * wn + 16 * bn + l15;
                b[bn] = *(const bf16x8*)(Bt + c * 64 + (((sbase + l4) ^ (c & 7)) << 3));
            }
            #pragma unroll
            for (int bn = 0; bn < 3; bn++)
                acc[bn] = __builtin_amdgcn_mfma_f32_16x16x32_bf16(a, b[bn], acc[bn], 0, 0, 0);
        }
        __syncthreads();
    }

    #pragma unroll
    for (int r = 0; r < 4; r++) {
        int row = row0 + 16 * wm + 4 * l4 + r;
        float rr = sigm(xr_[r] + acc[0][r] + bh0);
        float zz = sigm(xz_[r] + acc[1][r] + bh1);
        float nn = tanh_fast(xn_[r] + rr * (acc[2][r] + bh2));
        float hnew = (step < len_[r]) ? ((1.f - zz) * nn + zz * hold_[r]) : hold_[r];
        hout_b[((size_t)row << 8) + j] = (bf16)hnew;
    }
}

// ---------------------------------------------------------------------------
// K4 (verified R8): logits = h_final(bf16) @ Wc^T + bc
// ---------------------------------------------------------------------------
__global__ __launch_bounds__(256) void cls_kernel(
    const bf16* __restrict__ h, const float* __restrict__ Wc,
    const float* __restrict__ bc, float* __restrict__ out)
{
    __shared__ float Wl[8 * 260];
    int tid = threadIdx.x;
    for (int i = tid; i < 2048; i += 256) { int c = i >> 8, k = i & 255; Wl[c * 260 + k] = Wc[i]; }
    __syncthreads();
    int o = blockIdx.x * 256 + tid;
    int row = o >> 3, c = o & 7;
    const bf16x8* hr = (const bf16x8*)(h + ((size_t)row << 8));
    const float* wr = Wl + c * 260;
    float acc1 = 0.f;
    #pragma unroll 8
    for (int k = 0; k < 32; k++) {
        bf16x8 a = hr[k];
        const float* b = wr + 8 * k;
        acc1 += (float)a[0] * b[0] + (float)a[1] * b[1] + (float)a[2] * b[2] + (float)a[3] * b[3]
              + (float)a[4] * b[4] + (float)a[5] * b[5] + (float)a[6] * b[6] + (float)a[7] * b[7];
    }
    out[o] = acc1 + bc[c];
}

extern "C" void kernel_launch(void* const* d_in, const int* in_sizes, int n_in,
                              void* d_out, int out_size, void* d_ws, size_t ws_size,
                              hipStream_t stream) {
    if (n_in < 18) return;
    const float* paper_x  = (const float*)d_in[0];
    const float* author_x = (const float*)d_in[1];
    const float* venue_x  = (const float*)d_in[2];
    const float* Wp   = (const float*)d_in[3];
    const float* bp   = (const float*)d_in[4];
    const float* Wa   = (const float*)d_in[5];
    const float* ba   = (const float*)d_in[6];
    const float* Wv   = (const float*)d_in[7];
    const float* bv   = (const float*)d_in[8];
    const float* W_ih = (const float*)d_in[9];
    const float* b_ih = (const float*)d_in[10];
    const float* W_hh = (const float*)d_in[11];
    const float* b_hh = (const float*)d_in[12];
    const float* Wc   = (const float*)d_in[13];
    const float* bc   = (const float*)d_in[14];
    const int* type_ids = (const int*)d_in[15];
    const int* node_ids = (const int*)d_in[16];
    const int* lengths  = (const int*)d_in[17];

    char* ws = (char*)d_ws;
    size_t off = 0;
    bf16* Wcat  = (bf16*)(ws + off); off += (size_t)256 * 224 * 2;
    bf16* Wih_p = (bf16*)(ws + off); off += (size_t)768 * 256 * 2;
    bf16* Whh_p = (bf16*)(ws + off); off += (size_t)768 * 256 * 2;
    float* bih_p = (float*)(ws + off); off += 768 * 4;
    float* bhh_p = (float*)(ws + off); off += 768 * 4;
    off = (off + 255) & ~(size_t)255;
    bf16* emb = (bf16*)(ws + off); off += (size_t)32768 * 256 * 2;
    bf16* gx  = (bf16*)(ws + off); off += (size_t)32768 * 768 * 2;
    bf16* h0b = (bf16*)(ws + off); off += (size_t)4096 * 256 * 2;
    bf16* h1b = (bf16*)(ws + off); off += (size_t)4096 * 256 * 2;
    if (ws_size < off) return;

    setup_weights<<<992, 256, 0, stream>>>(Wp, Wa, Wv, W_ih, b_ih, W_hh, b_hh,
                                           Wcat, Wih_p, Whh_p, bih_p, bhh_p);
    emb_kernel<<<1024, 256, 0, stream>>>(paper_x, author_x, venue_x, bp, ba, bv,
                                         type_ids, node_ids, Wcat, emb);
    // gx + fused step 0 (writes h1b)
    gx_kernel<<<dim3(256, 8), 256, 0, stream>>>(emb, Wih_p, bih_p, bhh_p,
                                                lengths, gx, h1b);

    // steps 1..7 ping-pong; final lands in h0b
    for (int l = 1; l < 8; l++) {
        const bf16* hib = (l & 1) ? h1b : h0b;
        bf16* hob = (l & 1) ? h0b : h1b;
        gru_kernel<<<dim3(128, 8), 256, 0, stream>>>(hib, Whh_p, bhh_p, gx,
                                                     lengths, hob, l);
    }
    cls_kernel<<<128, 256, 0, stream>>>(h0b, Wc, bc, (float*)d_out);
}